// Round 7
// baseline (137.602 us; speedup 1.0000x reference)
//
#include <hip/hip_runtime.h>
#include <math.h>

typedef _Float16 half8 __attribute__((ext_vector_type(8)));
typedef _Float16 half4v __attribute__((ext_vector_type(4)));
typedef float f32x4 __attribute__((ext_vector_type(4)));

// Problem constants
#define BB 32
#define SS 8
#define PP 32
#define SENT 44
#define LL 352          // SS*SENT
#define TT 384          // PP+LL
#define DD 2048
#define H1 512
#define H2 768
#define MM (BB*TT)      // 12288
#define OUT0 (MM*H2)    // 9437184

// async global->LDS, 16B per lane, dest = wave-uniform base + lane*16,
// global source address IS per-lane.
#define GLL16(g, l) __builtin_amdgcn_global_load_lds( \
    (const __attribute__((address_space(1))) void*)(g), \
    (__attribute__((address_space(3))) void*)(l), 16, 0, 0)

// ---------------------------------------------------------------------------
// Transpose + fp32->fp16 convert:  dst[C][R] = (f16) src[R][C]
// ---------------------------------------------------------------------------
__global__ __launch_bounds__(256) void transpose_f16_kernel(
    const float* __restrict__ src, _Float16* __restrict__ dst, int R, int C)
{
    __shared__ float tile[32][33];
    int c0 = blockIdx.x * 32;
    int r0 = blockIdx.y * 32;
    int tx = threadIdx.x & 31;
    int ty = threadIdx.x >> 5;   // 0..7
    #pragma unroll
    for (int i = 0; i < 4; ++i)
        tile[ty + i*8][tx] = src[(size_t)(r0 + ty + i*8) * C + c0 + tx];
    __syncthreads();
    #pragma unroll
    for (int i = 0; i < 4; ++i)
        dst[(size_t)(c0 + ty + i*8) * R + r0 + tx] = (_Float16)tile[tx][ty + i*8];
}

// ---------------------------------------------------------------------------
// Staging macros for 64-half rows (c1 kernel): 4 threads/row, 16 elems each.
// XOR swizzle (row&7)<<3 in half units.
// ---------------------------------------------------------------------------
#define LOADA_T(S, ap, k0) {                                               \
    const float* _p = (ap) + (k0) + akq;                                   \
    float4 v0 = *(const float4*)(_p);                                      \
    float4 v1 = *(const float4*)(_p + 4);                                  \
    float4 v2 = *(const float4*)(_p + 8);                                  \
    float4 v3 = *(const float4*)(_p + 12);                                 \
    S[0]=v0.x; S[1]=v0.y; S[2]=v0.z; S[3]=v0.w;                            \
    S[4]=v1.x; S[5]=v1.y; S[6]=v1.z; S[7]=v1.w;                            \
    S[8]=v2.x; S[9]=v2.y; S[10]=v2.z; S[11]=v2.w;                          \
    S[12]=v3.x; S[13]=v3.y; S[14]=v3.z; S[15]=v3.w;                        \
}

#define WRITEA_T(S, dst) {                                                 \
    half8 h0, h1;                                                          \
    _Pragma("unroll")                                                      \
    for (int _j = 0; _j < 8; ++_j) { h0[_j] = (_Float16)S[_j];             \
                                     h1[_j] = (_Float16)S[8 + _j]; }       \
    *(half8*)&dst[(arow * 64 + akq) ^ aswz]     = h0;                      \
    *(half8*)&dst[(arow * 64 + akq + 8) ^ aswz] = h1;                      \
}

// ---------------------------------------------------------------------------
// C1 = concat_output @ W1 : [256, 512] fp32.  Tiny MFMA GEMM, grid 16,
// tile 64x128, BK=64, 4 waves (wave 32x64, 2x4 frags).
// ---------------------------------------------------------------------------
__global__ __launch_bounds__(256) void c1_kernel(
    const float*    __restrict__ concat_output,
    const _Float16* __restrict__ W1T,
    float*          __restrict__ C1)
{
    const int tid  = threadIdx.x;
    const int wid  = tid >> 6;
    const int lane = tid & 63;
    const int bm = blockIdx.x >> 2;    // 0..3
    const int bn = blockIdx.x & 3;     // 0..3

    __shared__ _Float16 As[2][64 * 64];
    __shared__ _Float16 Bs[2][128 * 64];

    const int arow = tid >> 2;
    const int akq  = (tid & 3) * 16;
    const int aswz = (arow & 7) << 3;
    const float* aptr = concat_output + (size_t)(bm * 64 + arow) * DD;

    const int rl = lane >> 3;
    const int cg = lane & 7;
    const _Float16* bsrc = W1T + (size_t)(bn * 128 + wid * 32 + rl) * DD
                               + ((cg ^ rl) << 3);

    #define C1B(buf, k0) {                                                \
        _Pragma("unroll")                                                 \
        for (int q = 0; q < 4; ++q)                                       \
            GLL16(bsrc + (size_t)q * 8 * DD + (k0),                       \
                  &Bs[buf][(wid * 4 + q) * 512]);                         \
    }

    const int wrow = (wid >> 1) * 32;
    const int wcol = (wid & 1) * 64;
    const int fr   = lane & 15;
    const int fg   = lane >> 4;

    f32x4 acc[2][4] = {};
    float a0[16], a1[16];

    C1B(0, 0);
    LOADA_T(a0, aptr, 0);
    LOADA_T(a1, aptr, 64);
    WRITEA_T(a0, As[0]);
    __syncthreads();

    #define C1_MFMA(buf) {                                                \
        _Pragma("unroll")                                                 \
        for (int kk = 0; kk < 2; ++kk) {                                  \
            half8 af[2], bf[4];                                           \
            _Pragma("unroll")                                             \
            for (int i = 0; i < 2; ++i) {                                 \
                int row = wrow + i * 16 + fr;                             \
                af[i] = *(const half8*)&As[buf][                          \
                    (row * 64 + kk * 32 + fg * 8) ^ ((row & 7) << 3)];    \
            }                                                             \
            _Pragma("unroll")                                             \
            for (int j = 0; j < 4; ++j) {                                 \
                int row = wcol + j * 16 + fr;                             \
                bf[j] = *(const half8*)&Bs[buf][                          \
                    (row * 64 + kk * 32 + fg * 8) ^ ((row & 7) << 3)];    \
            }                                                             \
            _Pragma("unroll")                                             \
            for (int i = 0; i < 2; ++i)                                   \
                _Pragma("unroll")                                         \
                for (int j = 0; j < 4; ++j)                               \
                    acc[i][j] = __builtin_amdgcn_mfma_f32_16x16x32_f16(   \
                        af[i], bf[j], acc[i][j], 0, 0, 0);                \
        }                                                                 \
    }

    for (int tt = 0; tt < 16; ++tt) {
        const int t2 = tt * 2;
        C1B(1, (t2 + 1) * 64);
        if (t2 + 2 < 32) LOADA_T(a0, aptr, (t2 + 2) * 64);
        C1_MFMA(0);
        WRITEA_T(a1, As[1]);
        __syncthreads();
        if (t2 + 2 < 32) C1B(0, (t2 + 2) * 64);
        if (t2 + 3 < 32) LOADA_T(a1, aptr, (t2 + 3) * 64);
        C1_MFMA(1);
        if (t2 + 2 < 32) WRITEA_T(a0, As[0]);
        __syncthreads();
    }

    #pragma unroll
    for (int i = 0; i < 2; ++i)
        #pragma unroll
        for (int j = 0; j < 4; ++j) {
            int col = bn * 128 + wcol + j * 16 + fr;
            #pragma unroll
            for (int r = 0; r < 4; ++r) {
                int row = bm * 64 + wrow + i * 16 + fg * 4 + r;
                C1[(size_t)row * H1 + col] = acc[i][j][r];
            }
        }
    #undef C1B
    #undef C1_MFMA
}

// ---------------------------------------------------------------------------
// GEMM1: H = tanh( gather(table) @ W1 + b1 + C1[crow] )
// FULL-N tile: BM=48, BN=512, BK=32. 512 threads = 8 waves; wave = 48x64
// (3x4 frags of 16x16x32). Grid = 256 = exactly 1 block/CU.
// Each gathered A-row is read from L3 exactly ONCE (fp32); W1T (2MB f16) is
// read by every block -> L2-resident. A reg-staged fp32->f16 (2-deep);
// B via GLL16 with both-sides XOR swizzle over 4 granules/row. LDS 70KB dbuf.
// ---------------------------------------------------------------------------
__global__ __launch_bounds__(512) void gemm1_kernel(
    const float*    __restrict__ token_table,
    const int*      __restrict__ topic_ids,
    const int*      __restrict__ input_ids,
    const _Float16* __restrict__ W1T,
    const float*    __restrict__ b1,
    const float*    __restrict__ C1,
    _Float16*       __restrict__ Hout)
{
    const int tid  = threadIdx.x;
    const int wid  = tid >> 6;       // 0..7
    const int lane = tid & 63;
    const int bm   = blockIdx.x;     // 0..255

    __shared__ _Float16 As[2][48 * 32];    //  3KB per buf
    __shared__ _Float16 Bs[2][512 * 32];   // 32KB per buf

    // --- A gather: threads 0..383, 8 threads/row, 4 fp32 each ---
    const int arow = tid >> 3;          // 0..63 (only <48 active)
    const int aseg = tid & 7;           // 4-float segment
    const bool aact = tid < 384;
    const float* aptr = token_table;    // overwritten below for active threads
    if (aact) {
        const int m = bm * 48 + arow;
        const int b = m / TT;
        const int t = m % TT;
        if (t < PP)
            aptr = token_table + (size_t)topic_ids[b * PP + t] * DD + aseg * 4;
        else
            aptr = token_table + (size_t)input_ids[b * LL + (t - PP)] * DD + aseg * 4;
    }
    // LDS write slot: granule (aseg>>1)^(arow&3), sub-half4 (aseg&1)
    const int awoff = arow * 32 + (((aseg >> 1) ^ (arow & 3)) << 3) + (aseg & 1) * 4;

    #define LOADA(S, k0) { if (aact) {                                     \
        float4 v = *(const float4*)(aptr + (k0));                          \
        S[0] = v.x; S[1] = v.y; S[2] = v.z; S[3] = v.w; } }

    #define WRITEA(S, buf) { if (aact) {                                   \
        half4v h;                                                          \
        h[0] = (_Float16)S[0]; h[1] = (_Float16)S[1];                      \
        h[2] = (_Float16)S[2]; h[3] = (_Float16)S[3];                      \
        *(half4v*)&As[buf][awoff] = h; } }

    // --- B staging: wave w stages rows [w*64, w*64+64) = 4 GLL16 ---
    const int rl = lane >> 2;           // 0..15 row within 16-row chunk
    const int cg = lane & 3;            // 16B granule within 64B row
    // pre-swizzled source: LDS granule (rl,cg) holds global granule cg^(rl&3)
    const _Float16* bsrc = W1T + (size_t)(wid * 64 + rl) * DD
                               + ((cg ^ (rl & 3)) << 3);

    #define G1B(buf, k0) {                                                 \
        _Pragma("unroll")                                                  \
        for (int q = 0; q < 4; ++q)                                        \
            GLL16(bsrc + (size_t)q * 16 * DD + (k0),                       \
                  &Bs[buf][(wid * 64 + q * 16) * 32]);                     \
    }

    // --- compute: wave covers rows 0..47, cols wid*64..+64 ---
    const int fr = lane & 15;
    const int fg = lane >> 4;           // 0..3

    f32x4 acc[3][4] = {};

    #define G1_MFMA(buf) {                                                 \
        half8 af[3], bf[4];                                                \
        _Pragma("unroll")                                                  \
        for (int i = 0; i < 3; ++i) {                                      \
            int row = i * 16 + fr;                                         \
            af[i] = *(const half8*)&As[buf][                               \
                row * 32 + ((fg ^ (row & 3)) << 3)];                       \
        }                                                                  \
        _Pragma("unroll")                                                  \
        for (int j = 0; j < 4; ++j) {                                      \
            int row = wid * 64 + j * 16 + fr;                              \
            bf[j] = *(const half8*)&Bs[buf][                               \
                row * 32 + ((fg ^ (row & 3)) << 3)];                       \
        }                                                                  \
        _Pragma("unroll")                                                  \
        for (int i = 0; i < 3; ++i)                                        \
            _Pragma("unroll")                                              \
            for (int j = 0; j < 4; ++j)                                    \
                acc[i][j] = __builtin_amdgcn_mfma_f32_16x16x32_f16(        \
                    af[i], bf[j], acc[i][j], 0, 0, 0);                     \
    }

    float a0[4], a1[4];

    // prologue
    G1B(0, 0);
    LOADA(a0, 0);
    LOADA(a1, 32);
    WRITEA(a0, 0);
    __syncthreads();

    // 64 K-steps as 32 double-phases
    for (int tt = 0; tt < 32; ++tt) {
        const int t2 = tt * 2;
        G1B(1, (t2 + 1) * 32);
        if (t2 + 2 < 64) LOADA(a0, (t2 + 2) * 32);
        G1_MFMA(0);
        WRITEA(a1, 1);
        __syncthreads();
        if (t2 + 2 < 64) G1B(0, (t2 + 2) * 32);
        if (t2 + 3 < 64) LOADA(a1, (t2 + 3) * 32);
        G1_MFMA(1);
        if (t2 + 2 < 64) WRITEA(a0, 0);
        __syncthreads();
    }

    // epilogue: + b1 + C1[crow] (input rows only), tanh, f16 store
    #pragma unroll
    for (int i = 0; i < 3; ++i) {
        #pragma unroll
        for (int j = 0; j < 4; ++j) {
            int col = wid * 64 + j * 16 + fr;
            float bias = b1[col];
            #pragma unroll
            for (int r = 0; r < 4; ++r) {
                int row = bm * 48 + i * 16 + fg * 4 + r;
                int rb = row / TT;
                int rt = row - rb * TT;
                float v = acc[i][j][r] + bias;
                if (rt >= PP)
                    v += C1[(size_t)(rb * SS + (rt - PP) / SENT) * H1 + col];
                Hout[(size_t)row * H1 + col] = (_Float16)tanhf(v);
            }
        }
    }
    #undef LOADA
    #undef WRITEA
    #undef G1B
    #undef G1_MFMA
}

// ---------------------------------------------------------------------------
// GEMM2: out = H @ W2 + b2.  H f16 [12288][512], W2T f16 [768][512],
// out f32 [12288][768]. Tile 96x192, BK=64, grid 512 = exactly 2 blocks/CU
// (LDS 72KB). Wave = 48x96 (3x6 frags). All-GLL16, both-sides swizzle.
// ---------------------------------------------------------------------------
__global__ __launch_bounds__(256) void gemm2_kernel(
    const _Float16* __restrict__ Hin,
    const _Float16* __restrict__ W2T,
    const float*    __restrict__ b2,
    float*          __restrict__ out)
{
    const int tid  = threadIdx.x;
    const int wid  = tid >> 6;
    const int lane = tid & 63;

    // 512 blocks, 64 per XCD; the 4 bn of a bm adjacent -> same XCD.
    const int logical = ((blockIdx.x & 7) * 64) + (blockIdx.x >> 3);
    const int bm = logical >> 2;     // 0..127
    const int bn = logical & 3;      // 0..3

    __shared__ _Float16 As[2][96 * 64];    // 12KB per buf
    __shared__ _Float16 Bs[2][192 * 64];   // 24KB per buf

    const int rl = lane >> 3;
    const int cg = lane & 7;
    const _Float16* asrc = Hin + (size_t)(bm * 96 + wid * 24 + rl) * H1
                               + ((cg ^ rl) << 3);
    const _Float16* bsrc = W2T + (size_t)(bn * 192 + wid * 48 + rl) * H1
                               + ((cg ^ rl) << 3);

    #define G2_ISSUE(buf, k0) {                                            \
        _Pragma("unroll")                                                 \
        for (int q = 0; q < 3; ++q)                                       \
            GLL16(asrc + (size_t)q * 8 * H1 + (k0),                       \
                  &As[buf][(wid * 3 + q) * 512]);                         \
        _Pragma("unroll")                                                 \
        for (int q = 0; q < 6; ++q)                                       \
            GLL16(bsrc + (size_t)q * 8 * H1 + (k0),                       \
                  &Bs[buf][(wid * 6 + q) * 512]);                         \
    }

    const int wrow = (wid >> 1) * 48;
    const int wcol = (wid & 1) * 96;
    const int fr   = lane & 15;
    const int fg   = lane >> 4;

    f32x4 acc[3][6] = {};

    G2_ISSUE(0, 0);

    const int NT = H1 / 64;   // 8
    for (int t = 0; t < NT; ++t) {
        __syncthreads();
        if (t + 1 < NT) G2_ISSUE((t + 1) & 1, (t + 1) * 64);
        const int cb = t & 1;
        #pragma unroll
        for (int kk = 0; kk < 2; ++kk) {
            half8 af[3], bf[6];
            #pragma unroll
            for (int i = 0; i < 3; ++i) {
                int row = wrow + i * 16 + fr;
                af[i] = *(const half8*)&As[cb][
                    (row * 64 + kk * 32 + fg * 8) ^ ((row & 7) << 3)];
            }
            #pragma unroll
            for (int j = 0; j < 6; ++j) {
                int row = wcol + j * 16 + fr;
                bf[j] = *(const half8*)&Bs[cb][
                    (row * 64 + kk * 32 + fg * 8) ^ ((row & 7) << 3)];
            }
            #pragma unroll
            for (int i = 0; i < 3; ++i)
                #pragma unroll
                for (int j = 0; j < 6; ++j)
                    acc[i][j] = __builtin_amdgcn_mfma_f32_16x16x32_f16(af[i], bf[j], acc[i][j], 0, 0, 0);
        }
    }

    #pragma unroll
    for (int i = 0; i < 3; ++i) {
        #pragma unroll
        for (int j = 0; j < 6; ++j) {
            int col = bn * 192 + wcol + j * 16 + fr;
            float bias = b2[col];
            #pragma unroll
            for (int r = 0; r < 4; ++r) {
                int row = bm * 96 + wrow + i * 16 + fg * 4 + r;
                out[(size_t)row * H2 + col] = acc[i][j][r] + bias;
            }
        }
    }
    #undef G2_ISSUE
}

// ---------------------------------------------------------------------------
// Aux outputs: labels / type_ids / att_mask concatenations, written as floats
// ---------------------------------------------------------------------------
__global__ __launch_bounds__(256) void aux_kernel(
    const int* __restrict__ topic_ids,
    const int* __restrict__ input_ids,
    const int* __restrict__ tpw_type_ids,
    const int* __restrict__ type_ids,
    const int* __restrict__ tpw_att_mask,
    const int* __restrict__ attention_mask,
    float* __restrict__ out)
{
    int idx = blockIdx.x * 256 + threadIdx.x;
    if (idx >= MM) return;
    int b = idx / TT, t = idx % TT;
    int lab, ty, mk;
    if (t < PP) {
        lab = topic_ids[b * PP + t];
        ty  = tpw_type_ids[b * PP + t];
        mk  = tpw_att_mask[b * PP + t];
    } else {
        int u = t - PP;
        lab = input_ids[b * LL + u];
        ty  = type_ids[b * LL + u];
        mk  = attention_mask[b * LL + u];
    }
    out[OUT0 + idx]          = (float)lab;
    out[OUT0 + MM + idx]     = (float)ty;
    out[OUT0 + 2 * MM + idx] = (float)mk;
}

extern "C" void kernel_launch(void* const* d_in, const int* in_sizes, int n_in,
                              void* d_out, int out_size, void* d_ws, size_t ws_size,
                              hipStream_t stream) {
    const float* concat_output  = (const float*)d_in[0];
    const int*   input_ids      = (const int*)d_in[1];
    const int*   topic_ids      = (const int*)d_in[2];
    const int*   tpw_att_mask   = (const int*)d_in[3];
    const int*   tpw_type_ids   = (const int*)d_in[4];
    const int*   attention_mask = (const int*)d_in[5];
    const int*   type_ids       = (const int*)d_in[6];
    const float* token_table    = (const float*)d_in[7];
    const float* W1             = (const float*)d_in[8];
    const float* b1             = (const float*)d_in[9];
    const float* W2             = (const float*)d_in[10];
    const float* b2             = (const float*)d_in[11];
    float* out = (float*)d_out;

    _Float16* w1t = (_Float16*)d_ws;            // [512][2048]   2.0 MB
    _Float16* w2t = w1t + (size_t)H1 * DD;      // [768][512]    0.75 MB
    _Float16* Hws = w2t + (size_t)H2 * H1;      // [12288][512]  12.6 MB
    float*    C1w = (float*)(Hws + (size_t)MM * H1);  // [256][512] f32 0.5 MB

    transpose_f16_kernel<<<dim3(H1 / 32, DD / 32), 256, 0, stream>>>(W1, w1t, DD, H1);
    transpose_f16_kernel<<<dim3(H2 / 32, H1 / 32), 256, 0, stream>>>(W2, w2t, H1, H2);
    aux_kernel<<<(MM + 255) / 256, 256, 0, stream>>>(
        topic_ids, input_ids, tpw_type_ids, type_ids, tpw_att_mask, attention_mask, out);
    c1_kernel<<<16, 256, 0, stream>>>(concat_output, w1t, C1w);

    gemm1_kernel<<<MM / 48, 512, 0, stream>>>(
        token_table, topic_ids, input_ids, w1t, b1, C1w, Hws);
    gemm2_kernel<<<(MM / 96) * (H2 / 192), 256, 0, stream>>>(Hws, w2t, b2, out);
}

// Round 8
// 130.396 us; speedup vs baseline: 1.0553x; 1.0553x over previous
//
#include <hip/hip_runtime.h>
#include <math.h>

typedef _Float16 half8 __attribute__((ext_vector_type(8)));
typedef float f32x4 __attribute__((ext_vector_type(4)));

// Problem constants
#define BB 32
#define SS 8
#define PP 32
#define SENT 44
#define LL 352          // SS*SENT
#define TT 384          // PP+LL
#define DD 2048
#define H1 512
#define H2 768
#define MM (BB*TT)      // 12288
#define OUT0 (MM*H2)    // 9437184

// async global->LDS, 16B per lane, dest = wave-uniform base + lane*16,
// global source address IS per-lane.
#define GLL16(g, l) __builtin_amdgcn_global_load_lds( \
    (const __attribute__((address_space(1))) void*)(g), \
    (__attribute__((address_space(3))) void*)(l), 16, 0, 0)

// ---------------------------------------------------------------------------
// Transpose + fp32->fp16 convert:  dst[C][R] = (f16) src[R][C]
// ---------------------------------------------------------------------------
__global__ __launch_bounds__(256) void transpose_f16_kernel(
    const float* __restrict__ src, _Float16* __restrict__ dst, int R, int C)
{
    __shared__ float tile[32][33];
    int c0 = blockIdx.x * 32;
    int r0 = blockIdx.y * 32;
    int tx = threadIdx.x & 31;
    int ty = threadIdx.x >> 5;   // 0..7
    #pragma unroll
    for (int i = 0; i < 4; ++i)
        tile[ty + i*8][tx] = src[(size_t)(r0 + ty + i*8) * C + c0 + tx];
    __syncthreads();
    #pragma unroll
    for (int i = 0; i < 4; ++i)
        dst[(size_t)(c0 + ty + i*8) * R + r0 + tx] = (_Float16)tile[tx][ty + i*8];
}

// ---------------------------------------------------------------------------
// Staging macros for 64-half rows (c1 kernel): 4 threads/row, 16 elems each.
// XOR swizzle (row&7)<<3 in half units.
// ---------------------------------------------------------------------------
#define LOADA_T(S, ap, k0) {                                               \
    const float* _p = (ap) + (k0) + akq;                                   \
    float4 v0 = *(const float4*)(_p);                                      \
    float4 v1 = *(const float4*)(_p + 4);                                  \
    float4 v2 = *(const float4*)(_p + 8);                                  \
    float4 v3 = *(const float4*)(_p + 12);                                 \
    S[0]=v0.x; S[1]=v0.y; S[2]=v0.z; S[3]=v0.w;                            \
    S[4]=v1.x; S[5]=v1.y; S[6]=v1.z; S[7]=v1.w;                            \
    S[8]=v2.x; S[9]=v2.y; S[10]=v2.z; S[11]=v2.w;                          \
    S[12]=v3.x; S[13]=v3.y; S[14]=v3.z; S[15]=v3.w;                        \
}

#define WRITEA_T(S, dst) {                                                 \
    half8 h0, h1;                                                          \
    _Pragma("unroll")                                                      \
    for (int _j = 0; _j < 8; ++_j) { h0[_j] = (_Float16)S[_j];             \
                                     h1[_j] = (_Float16)S[8 + _j]; }       \
    *(half8*)&dst[(arow * 64 + akq) ^ aswz]     = h0;                      \
    *(half8*)&dst[(arow * 64 + akq + 8) ^ aswz] = h1;                      \
}

// ---------------------------------------------------------------------------
// C1 = concat_output @ W1 : [256, 512] fp32.  Tiny MFMA GEMM, grid 16.
// ---------------------------------------------------------------------------
__global__ __launch_bounds__(256) void c1_kernel(
    const float*    __restrict__ concat_output,
    const _Float16* __restrict__ W1T,
    float*          __restrict__ C1)
{
    const int tid  = threadIdx.x;
    const int wid  = tid >> 6;
    const int lane = tid & 63;
    const int bm = blockIdx.x >> 2;    // 0..3
    const int bn = blockIdx.x & 3;     // 0..3

    __shared__ _Float16 As[2][64 * 64];
    __shared__ _Float16 Bs[2][128 * 64];

    const int arow = tid >> 2;
    const int akq  = (tid & 3) * 16;
    const int aswz = (arow & 7) << 3;
    const float* aptr = concat_output + (size_t)(bm * 64 + arow) * DD;

    const int rl = lane >> 3;
    const int cg = lane & 7;
    const _Float16* bsrc = W1T + (size_t)(bn * 128 + wid * 32 + rl) * DD
                               + ((cg ^ rl) << 3);

    #define C1B(buf, k0) {                                                \
        _Pragma("unroll")                                                 \
        for (int q = 0; q < 4; ++q)                                       \
            GLL16(bsrc + (size_t)q * 8 * DD + (k0),                       \
                  &Bs[buf][(wid * 4 + q) * 512]);                         \
    }

    const int wrow = (wid >> 1) * 32;
    const int wcol = (wid & 1) * 64;
    const int fr   = lane & 15;
    const int fg   = lane >> 4;

    f32x4 acc[2][4] = {};
    float a0[16], a1[16];

    C1B(0, 0);
    LOADA_T(a0, aptr, 0);
    LOADA_T(a1, aptr, 64);
    WRITEA_T(a0, As[0]);
    __syncthreads();

    #define C1_MFMA(buf) {                                                \
        _Pragma("unroll")                                                 \
        for (int kk = 0; kk < 2; ++kk) {                                  \
            half8 af[2], bf[4];                                           \
            _Pragma("unroll")                                             \
            for (int i = 0; i < 2; ++i) {                                 \
                int row = wrow + i * 16 + fr;                             \
                af[i] = *(const half8*)&As[buf][                          \
                    (row * 64 + kk * 32 + fg * 8) ^ ((row & 7) << 3)];    \
            }                                                             \
            _Pragma("unroll")                                             \
            for (int j = 0; j < 4; ++j) {                                 \
                int row = wcol + j * 16 + fr;                             \
                bf[j] = *(const half8*)&Bs[buf][                          \
                    (row * 64 + kk * 32 + fg * 8) ^ ((row & 7) << 3)];    \
            }                                                             \
            _Pragma("unroll")                                             \
            for (int i = 0; i < 2; ++i)                                   \
                _Pragma("unroll")                                         \
                for (int j = 0; j < 4; ++j)                               \
                    acc[i][j] = __builtin_amdgcn_mfma_f32_16x16x32_f16(   \
                        af[i], bf[j], acc[i][j], 0, 0, 0);                \
        }                                                                 \
    }

    for (int tt = 0; tt < 16; ++tt) {
        const int t2 = tt * 2;
        C1B(1, (t2 + 1) * 64);
        if (t2 + 2 < 32) LOADA_T(a0, aptr, (t2 + 2) * 64);
        C1_MFMA(0);
        WRITEA_T(a1, As[1]);
        __syncthreads();
        if (t2 + 2 < 32) C1B(0, (t2 + 2) * 64);
        if (t2 + 3 < 32) LOADA_T(a1, aptr, (t2 + 3) * 64);
        C1_MFMA(1);
        if (t2 + 2 < 32) WRITEA_T(a0, As[0]);
        __syncthreads();
    }

    #pragma unroll
    for (int i = 0; i < 2; ++i)
        #pragma unroll
        for (int j = 0; j < 4; ++j) {
            int col = bn * 128 + wcol + j * 16 + fr;
            #pragma unroll
            for (int r = 0; r < 4; ++r) {
                int row = bm * 64 + wrow + i * 16 + fg * 4 + r;
                C1[(size_t)row * H1 + col] = acc[i][j][r];
            }
        }
    #undef C1B
    #undef C1_MFMA
}

// ---------------------------------------------------------------------------
// GEMM1: H = tanh( gather(table) @ W1 + b1 + C1[crow] )
// BM=96, BN=256, BK=64. Grid 256 = exactly 1 block/CU. 512 thr = 8 waves,
// wave = 48x64 (3x4 frags of mfma_f32_16x16x32_f16, 24 MFMA/step).
// ALL staging via global_load_lds: A as fp32 (ring-2, 1-step lead, converted
// to f16 on LDS read), B as f16 (ring-3, 2-step lead). Counted
// s_waitcnt vmcnt(11) + raw s_barrier — loads stay in flight across barriers
// (T3+T4). setprio(1) around the MFMA cluster (T5). Both-sides granule XOR
// swizzle (T2). LDS = 2*24KB + 3*32KB = 144KB.
// ---------------------------------------------------------------------------
__global__ __launch_bounds__(512) void gemm1_kernel(
    const float*    __restrict__ token_table,
    const int*      __restrict__ topic_ids,
    const int*      __restrict__ input_ids,
    const _Float16* __restrict__ W1T,
    const float*    __restrict__ b1,
    const float*    __restrict__ C1,
    _Float16*       __restrict__ Hout)
{
    const int tid  = threadIdx.x;
    const int wid  = tid >> 6;       // 0..7
    const int lane = tid & 63;

    // 256 blocks, 32 per XCD (bijective); the 2 bn of a bm are adjacent.
    const int logical = ((blockIdx.x & 7) * 32) + (blockIdx.x >> 3);
    const int bm = logical >> 1;     // 0..127
    const int bn = logical & 1;      // 0..1

    __shared__ float    As[2][96 * 64];     // fp32 A, 24KB per buf
    __shared__ _Float16 Bs[3][256 * 64];    // f16  B, 32KB per buf

    // ---- A gather sources: 3 GLL16 per wave, 4 rows each, granule-swizzled
    const float* asrc[3];
    #pragma unroll
    for (int q = 0; q < 3; ++q) {
        const int ridx = wid * 12 + q * 4 + (lane >> 4);   // tile-local row
        const int m = bm * 96 + ridx;
        const int b = m / TT;
        const int t = m % TT;
        const int id = (t < PP) ? topic_ids[b * PP + t]
                                : input_ids[b * LL + (t - PP)];
        asrc[q] = token_table + (size_t)id * DD
                + (((lane & 15) ^ (ridx & 7)) << 2);       // 16B granule (4 f32)
    }
    // ---- B sources: 4 GLL16 per wave, 8 rows each, granule-swizzled ----
    const _Float16* bsrc[4];
    #pragma unroll
    for (int q = 0; q < 4; ++q) {
        const int ridx = wid * 32 + q * 8 + (lane >> 3);
        bsrc[q] = W1T + (size_t)(bn * 256 + ridx) * DD
                + (((lane & 7) ^ (ridx & 7)) << 3);        // 16B granule (8 f16)
    }

    #define ISSA(t, slot) {                                                  \
        _Pragma("unroll")                                                    \
        for (int q = 0; q < 3; ++q)                                          \
            GLL16(asrc[q] + (t) * 64, &As[slot][(wid * 12 + q * 4) * 64]);   \
    }
    #define ISSB(t, slot) {                                                  \
        _Pragma("unroll")                                                    \
        for (int q = 0; q < 4; ++q)                                          \
            GLL16(bsrc[q] + (t) * 64, &Bs[slot][(wid * 32 + q * 8) * 64]);   \
    }

    // ---- compute assignment: wave (wr,wc) -> 48 rows x 64 cols ----
    const int wr = wid >> 2;         // 0..1
    const int wc = wid & 3;          // 0..3
    const int fr = lane & 15;
    const int fg = lane >> 4;
    const int sw = fr & 7;           // = row&7 for all frag reads

    f32x4 acc[3][4] = {};

    #define MSTEP(aslot, bslot) {                                            \
        _Pragma("unroll")                                                    \
        for (int kk = 0; kk < 2; ++kk) {                                     \
            half8 af[3], bf[4];                                              \
            _Pragma("unroll")                                                \
            for (int i = 0; i < 3; ++i) {                                    \
                int row = wr * 48 + i * 16 + fr;                             \
                int g0 = kk * 8 + fg * 2;                                    \
                f32x4 lo = *(const f32x4*)&As[aslot][row * 64 + ((g0 ^ sw) << 2)];       \
                f32x4 hi = *(const f32x4*)&As[aslot][row * 64 + (((g0 + 1) ^ sw) << 2)]; \
                half8 h;                                                     \
                h[0]=(_Float16)lo[0]; h[1]=(_Float16)lo[1];                  \
                h[2]=(_Float16)lo[2]; h[3]=(_Float16)lo[3];                  \
                h[4]=(_Float16)hi[0]; h[5]=(_Float16)hi[1];                  \
                h[6]=(_Float16)hi[2]; h[7]=(_Float16)hi[3];                  \
                af[i] = h;                                                   \
            }                                                                \
            _Pragma("unroll")                                                \
            for (int j = 0; j < 4; ++j) {                                    \
                int row = wc * 64 + j * 16 + fr;                             \
                int g = kk * 4 + fg;                                         \
                bf[j] = *(const half8*)&Bs[bslot][row * 64 + ((g ^ sw) << 3)]; \
            }                                                                \
            _Pragma("unroll")                                                \
            for (int i = 0; i < 3; ++i)                                      \
                _Pragma("unroll")                                            \
                for (int j = 0; j < 4; ++j)                                  \
                    acc[i][j] = __builtin_amdgcn_mfma_f32_16x16x32_f16(      \
                        af[i], bf[j], acc[i][j], 0, 0, 0);                   \
        }                                                                    \
    }

    // prologue: A0, B0, B1 in flight (11 outstanding per wave)
    ISSA(0, 0);
    ISSB(0, 0);
    ISSB(1, 1);

    // steady loop: t = 0..29  (32 K-steps total; last two peeled)
    for (int t = 0; t < 30; ++t) {
        __builtin_amdgcn_s_barrier();               // ends step t-1's LDS reads
        __builtin_amdgcn_sched_barrier(0);
        ISSA(t + 1, (t + 1) & 1);
        ISSB(t + 2, (t + 2) % 3);
        asm volatile("s_waitcnt vmcnt(11)" ::: "memory");   // A[t],B[t] landed
        __builtin_amdgcn_sched_barrier(0);
        __builtin_amdgcn_s_barrier();               // all waves' stages visible
        __builtin_amdgcn_sched_barrier(0);
        __builtin_amdgcn_s_setprio(1);
        MSTEP(t & 1, t % 3);
        __builtin_amdgcn_s_setprio(0);
    }
    // t = 30: issue A[31] only; outstanding after wait = B31(4)+A31(3) = 7
    {
        __builtin_amdgcn_s_barrier();
        __builtin_amdgcn_sched_barrier(0);
        ISSA(31, 1);
        asm volatile("s_waitcnt vmcnt(7)" ::: "memory");
        __builtin_amdgcn_sched_barrier(0);
        __builtin_amdgcn_s_barrier();
        __builtin_amdgcn_sched_barrier(0);
        __builtin_amdgcn_s_setprio(1);
        MSTEP(0, 0);                                // 30&1=0, 30%3=0
        __builtin_amdgcn_s_setprio(0);
    }
    // t = 31: nothing left to issue
    {
        __builtin_amdgcn_s_barrier();
        __builtin_amdgcn_sched_barrier(0);
        asm volatile("s_waitcnt vmcnt(0)" ::: "memory");
        __builtin_amdgcn_sched_barrier(0);
        __builtin_amdgcn_s_barrier();
        __builtin_amdgcn_sched_barrier(0);
        __builtin_amdgcn_s_setprio(1);
        MSTEP(1, 1);                                // 31&1=1, 31%3=1
        __builtin_amdgcn_s_setprio(0);
    }

    // epilogue: + b1 + C1[crow] (input rows only), tanh, f16 store
    #pragma unroll
    for (int i = 0; i < 3; ++i) {
        #pragma unroll
        for (int j = 0; j < 4; ++j) {
            int col = bn * 256 + wc * 64 + j * 16 + fr;
            float bias = b1[col];
            #pragma unroll
            for (int r = 0; r < 4; ++r) {
                int row = bm * 96 + wr * 48 + i * 16 + fg * 4 + r;
                int rb = row / TT;
                int rt = row - rb * TT;
                float v = acc[i][j][r] + bias;
                if (rt >= PP)
                    v += C1[(size_t)(rb * SS + (rt - PP) / SENT) * H1 + col];
                Hout[(size_t)row * H1 + col] = (_Float16)tanhf(v);
            }
        }
    }
    #undef ISSA
    #undef ISSB
    #undef MSTEP
}

// ---------------------------------------------------------------------------
// GEMM2: out = H @ W2 + b2.  H f16 [12288][512], W2T f16 [768][512],
// out f32 [12288][768]. Tile 128x128, BK=64, wave = 64x64 (4x4 frags).
// Proven R5 version (GLL16, linear LDS, 2-phase). Grid 576.
// ---------------------------------------------------------------------------
__global__ __launch_bounds__(256) void gemm2_kernel(
    const _Float16* __restrict__ Hin,
    const _Float16* __restrict__ W2T,
    const float*    __restrict__ b2,
    float*          __restrict__ out)
{
    const int tid  = threadIdx.x;
    const int wid  = tid >> 6;
    const int lane = tid & 63;

    // 576 blocks, 72 per XCD
    const int logical = ((blockIdx.x & 7) * 72) + (blockIdx.x >> 3);
    const int bm = logical / 6;      // 0..95
    const int bn = logical % 6;      // 0..5

    __shared__ _Float16 As[2][128 * 64];   // 16KB per buf
    __shared__ _Float16 Bs[2][128 * 64];

    const int lrow = lane >> 3;
    const int lcol = (lane & 7) * 8;
    const _Float16* ag[4];
    const _Float16* bg[4];
    #pragma unroll
    for (int q = 0; q < 4; ++q) {
        ag[q] = Hin + (size_t)(bm * 128 + (wid + q * 4) * 8 + lrow) * H1 + lcol;
        bg[q] = W2T + (size_t)(bn * 128 + (wid + q * 4) * 8 + lrow) * H1 + lcol;
    }

    #define G2_ISSUE(buf, k0) {                                        \
        _Pragma("unroll")                                              \
        for (int q = 0; q < 4; ++q) {                                  \
            GLL16(ag[q] + (k0), &As[buf][(wid + q * 4) * 512]);        \
            GLL16(bg[q] + (k0), &Bs[buf][(wid + q * 4) * 512]);        \
        }                                                              \
    }

    const int wrow = (wid >> 1) * 64;
    const int wcol = (wid & 1) * 64;
    const int fr   = lane & 15;
    const int fg   = lane >> 4;

    f32x4 acc[4][4] = {};

    G2_ISSUE(0, 0);

    const int NT = H1 / 64;   // 8
    for (int t = 0; t < NT; ++t) {
        __syncthreads();
        if (t + 1 < NT) G2_ISSUE((t + 1) & 1, (t + 1) * 64);
        const int cb = t & 1;
        #pragma unroll
        for (int kk = 0; kk < 2; ++kk) {
            half8 af[4], bf[4];
            #pragma unroll
            for (int i = 0; i < 4; ++i)
                af[i] = *(const half8*)&As[cb][(wrow + i*16 + fr) * 64 + kk*32 + fg*8];
            #pragma unroll
            for (int j = 0; j < 4; ++j)
                bf[j] = *(const half8*)&Bs[cb][(wcol + j*16 + fr) * 64 + kk*32 + fg*8];
            #pragma unroll
            for (int i = 0; i < 4; ++i)
                #pragma unroll
                for (int j = 0; j < 4; ++j)
                    acc[i][j] = __builtin_amdgcn_mfma_f32_16x16x32_f16(af[i], bf[j], acc[i][j], 0, 0, 0);
        }
    }

    #pragma unroll
    for (int i = 0; i < 4; ++i) {
        #pragma unroll
        for (int j = 0; j < 4; ++j) {
            int col = bn * 128 + wcol + j * 16 + fr;
            float bias = b2[col];
            #pragma unroll
            for (int r = 0; r < 4; ++r) {
                int row = bm * 128 + wrow + i * 16 + fg * 4 + r;
                out[(size_t)row * H2 + col] = acc[i][j][r] + bias;
            }
        }
    }
    #undef G2_ISSUE
}

// ---------------------------------------------------------------------------
// Aux outputs: labels / type_ids / att_mask concatenations, written as floats
// ---------------------------------------------------------------------------
__global__ __launch_bounds__(256) void aux_kernel(
    const int* __restrict__ topic_ids,
    const int* __restrict__ input_ids,
    const int* __restrict__ tpw_type_ids,
    const int* __restrict__ type_ids,
    const int* __restrict__ tpw_att_mask,
    const int* __restrict__ attention_mask,
    float* __restrict__ out)
{
    int idx = blockIdx.x * 256 + threadIdx.x;
    if (idx >= MM) return;
    int b = idx / TT, t = idx % TT;
    int lab, ty, mk;
    if (t < PP) {
        lab = topic_ids[b * PP + t];
        ty  = tpw_type_ids[b * PP + t];
        mk  = tpw_att_mask[b * PP + t];
    } else {
        int u = t - PP;
        lab = input_ids[b * LL + u];
        ty  = type_ids[b * LL + u];
        mk  = attention_mask[b * LL + u];
    }
    out[OUT0 + idx]          = (float)lab;
    out[OUT0 + MM + idx]     = (float)ty;
    out[OUT0 + 2 * MM + idx] = (float)mk;
}

extern "C" void kernel_launch(void* const* d_in, const int* in_sizes, int n_in,
                              void* d_out, int out_size, void* d_ws, size_t ws_size,
                              hipStream_t stream) {
    const float* concat_output  = (const float*)d_in[0];
    const int*   input_ids      = (const int*)d_in[1];
    const int*   topic_ids      = (const int*)d_in[2];
    const int*   tpw_att_mask   = (const int*)d_in[3];
    const int*   tpw_type_ids   = (const int*)d_in[4];
    const int*   attention_mask = (const int*)d_in[5];
    const int*   type_ids       = (const int*)d_in[6];
    const float* token_table    = (const float*)d_in[7];
    const float* W1             = (const float*)d_in[8];
    const float* b1             = (const float*)d_in[9];
    const float* W2             = (const float*)d_in[10];
    const float* b2             = (const float*)d_in[11];
    float* out = (float*)d_out;

    _Float16* w1t = (_Float16*)d_ws;            // [512][2048]   2.0 MB
    _Float16* w2t = w1t + (size_t)H1 * DD;      // [768][512]    0.75 MB
    _Float16* Hws = w2t + (size_t)H2 * H1;      // [12288][512]  12.6 MB
    float*    C1w = (float*)(Hws + (size_t)MM * H1);  // [256][512] f32 0.5 MB

    transpose_f16_kernel<<<dim3(H1 / 32, DD / 32), 256, 0, stream>>>(W1, w1t, DD, H1);
    transpose_f16_kernel<<<dim3(H2 / 32, H1 / 32), 256, 0, stream>>>(W2, w2t, H1, H2);
    aux_kernel<<<(MM + 255) / 256, 256, 0, stream>>>(
        topic_ids, input_ids, tpw_type_ids, type_ids, tpw_att_mask, attention_mask, out);
    c1_kernel<<<16, 256, 0, stream>>>(concat_output, w1t, C1w);

    gemm1_kernel<<<(MM / 96) * 2, 512, 0, stream>>>(
        token_table, topic_ids, input_ids, w1t, b1, C1w, Hws);
    gemm2_kernel<<<(MM / 128) * (H2 / 128), 256, 0, stream>>>(Hws, w2t, b2, out);
}

// Round 9
// 121.389 us; speedup vs baseline: 1.1336x; 1.0742x over previous
//
#include <hip/hip_runtime.h>
#include <math.h>

typedef _Float16 half8 __attribute__((ext_vector_type(8)));
typedef float f32x4 __attribute__((ext_vector_type(4)));

// Problem constants
#define BB 32
#define SS 8
#define PP 32
#define SENT 44
#define LL 352          // SS*SENT
#define TT 384          // PP+LL
#define DD 2048
#define H1 512
#define H2 768
#define MM (BB*TT)      // 12288
#define OUT0 (MM*H2)    // 9437184

// async global->LDS, 16B per lane, dest = wave-uniform base + lane*16,
// global source address IS per-lane.
#define GLL16(g, l) __builtin_amdgcn_global_load_lds( \
    (const __attribute__((address_space(1))) void*)(g), \
    (__attribute__((address_space(3))) void*)(l), 16, 0, 0)

// ---------------------------------------------------------------------------
// Gather + concat-add + fp32->f16:  A16[m][k], m in [0,12288), k in [0,2048)
// One block per row, 256 threads x 8 elems. Streaming, latency-tolerant
// (48 blocks/CU of TLP) — this decouples the random-row latency from the
// barrier-synced MFMA loop, which R7/R8 proved is the gemm1 plateau cause.
// ---------------------------------------------------------------------------
__global__ __launch_bounds__(256) void gather_kernel(
    const float* __restrict__ token_table,
    const int*   __restrict__ topic_ids,
    const int*   __restrict__ input_ids,
    const float* __restrict__ concat_output,
    _Float16*    __restrict__ A16)
{
    const int m = blockIdx.x;
    const int b = m / TT;
    const int t = m % TT;
    const float* src;
    const float* addp = nullptr;
    if (t < PP) {
        src = token_table + (size_t)topic_ids[b * PP + t] * DD;
    } else {
        int u = t - PP;
        src = token_table + (size_t)input_ids[b * LL + u] * DD;
        addp = concat_output + ((size_t)b * SS + (u / SENT)) * DD;
    }
    _Float16* dst = A16 + (size_t)m * DD;
    const int base = threadIdx.x * 8;
    float4 v0 = *(const float4*)(src + base);
    float4 v1 = *(const float4*)(src + base + 4);
    if (addp) {
        float4 c0 = *(const float4*)(addp + base);
        float4 c1 = *(const float4*)(addp + base + 4);
        v0.x += c0.x; v0.y += c0.y; v0.z += c0.z; v0.w += c0.w;
        v1.x += c1.x; v1.y += c1.y; v1.z += c1.z; v1.w += c1.w;
    }
    half8 h;
    h[0] = (_Float16)v0.x; h[1] = (_Float16)v0.y; h[2] = (_Float16)v0.z; h[3] = (_Float16)v0.w;
    h[4] = (_Float16)v1.x; h[5] = (_Float16)v1.y; h[6] = (_Float16)v1.z; h[7] = (_Float16)v1.w;
    *(half8*)(dst + base) = h;
}

// ---------------------------------------------------------------------------
// Transpose + fp32->fp16 convert:  dst[C][R] = (f16) src[R][C]
// ---------------------------------------------------------------------------
__global__ __launch_bounds__(256) void transpose_f16_kernel(
    const float* __restrict__ src, _Float16* __restrict__ dst, int R, int C)
{
    __shared__ float tile[32][33];
    int c0 = blockIdx.x * 32;
    int r0 = blockIdx.y * 32;
    int tx = threadIdx.x & 31;
    int ty = threadIdx.x >> 5;   // 0..7
    #pragma unroll
    for (int i = 0; i < 4; ++i)
        tile[ty + i*8][tx] = src[(size_t)(r0 + ty + i*8) * C + c0 + tx];
    __syncthreads();
    #pragma unroll
    for (int i = 0; i < 4; ++i)
        dst[(size_t)(c0 + ty + i*8) * R + r0 + tx] = (_Float16)tile[tx][ty + i*8];
}

// ---------------------------------------------------------------------------
// GEMM1: H = tanh( A16 @ W1 + b1 ).  A16 f16 [12288][2048] (gather+concat
// already applied), W1T f16 [512][2048], H f16 [12288][512].
// Tile 64x256, BK=64, 256 thr = 4 waves, wave = 32x128 (2x8 frags).
// Both operands via GLL16 with both-sides XOR swizzle (pre-swizzled global
// source + swizzled LDS read — T2, proven in R5). Proven single-barrier
// 2-phase dbuf loop. Grid 384 XCD-chunked (48/XCD; both bn of a bm adjacent
// -> A16 rows L2-reused). LDS 80KB.
// A16 re-read = 2x (100 MB L3); B total = 384 MB from L2-resident W1T.
// ---------------------------------------------------------------------------
__global__ __launch_bounds__(256) void gemm1_kernel(
    const _Float16* __restrict__ A16,
    const _Float16* __restrict__ W1T,
    const float*    __restrict__ b1,
    _Float16*       __restrict__ Hout)
{
    const int tid  = threadIdx.x;
    const int wid  = tid >> 6;
    const int lane = tid & 63;

    // 384 blocks, 48 per XCD (bijective)
    const int logical = ((blockIdx.x & 7) * 48) + (blockIdx.x >> 3);
    const int bm = logical >> 1;     // 0..191
    const int bn = logical & 1;      // 0..1

    __shared__ _Float16 As[2][64 * 64];     // 16KB total
    __shared__ _Float16 Bs[2][256 * 64];    // 64KB total

    // staging lanes: 8 rows per GLL16, granule-swizzled source
    const int rl = lane >> 3;            // 0..7 row within 8-row chunk
    const int cg = lane & 7;             // 16B granule within 128B row
    const _Float16* asrc = A16 + (size_t)(bm * 64 + wid * 16 + rl) * DD
                               + ((cg ^ rl) << 3);
    const _Float16* bsrc = W1T + (size_t)(bn * 256 + wid * 64 + rl) * DD
                               + ((cg ^ rl) << 3);

    #define G1_ISSUE(buf, k0) {                                            \
        _Pragma("unroll")                                                  \
        for (int q = 0; q < 2; ++q)                                        \
            GLL16(asrc + (size_t)q * 8 * DD + (k0),                        \
                  &As[buf][(wid * 16 + q * 8) * 64]);                      \
        _Pragma("unroll")                                                  \
        for (int q = 0; q < 8; ++q)                                        \
            GLL16(bsrc + (size_t)q * 8 * DD + (k0),                        \
                  &Bs[buf][(wid * 64 + q * 8) * 64]);                      \
    }

    // compute: wave -> 32 rows x 128 cols (2x8 frags of 16x16x32)
    const int wrow = (wid >> 1) * 32;
    const int wcol = (wid & 1) * 128;
    const int fr   = lane & 15;
    const int fg   = lane >> 4;

    f32x4 acc[2][8] = {};

    G1_ISSUE(0, 0);

    const int NT = DD / 64;   // 32
    for (int t = 0; t < NT; ++t) {
        __syncthreads();                     // drains vmcnt: buf[t&1] ready
        if (t + 1 < NT) G1_ISSUE((t + 1) & 1, (t + 1) * 64);
        const int cb = t & 1;
        #pragma unroll
        for (int kk = 0; kk < 2; ++kk) {
            half8 af[2], bf[8];
            #pragma unroll
            for (int i = 0; i < 2; ++i) {
                int row = wrow + i * 16 + fr;
                af[i] = *(const half8*)&As[cb][
                    (row * 64 + kk * 32 + fg * 8) ^ ((row & 7) << 3)];
            }
            #pragma unroll
            for (int j = 0; j < 8; ++j) {
                int row = wcol + j * 16 + fr;
                bf[j] = *(const half8*)&Bs[cb][
                    (row * 64 + kk * 32 + fg * 8) ^ ((row & 7) << 3)];
            }
            #pragma unroll
            for (int i = 0; i < 2; ++i)
                #pragma unroll
                for (int j = 0; j < 8; ++j)
                    acc[i][j] = __builtin_amdgcn_mfma_f32_16x16x32_f16(
                        af[i], bf[j], acc[i][j], 0, 0, 0);
        }
    }

    // epilogue: bias + tanh -> f16 H
    #pragma unroll
    for (int i = 0; i < 2; ++i) {
        #pragma unroll
        for (int j = 0; j < 8; ++j) {
            int col = bn * 256 + wcol + j * 16 + fr;
            float bias = b1[col];
            #pragma unroll
            for (int r = 0; r < 4; ++r) {
                int row = bm * 64 + wrow + i * 16 + fg * 4 + r;
                Hout[(size_t)row * H1 + col] = (_Float16)tanhf(acc[i][j][r] + bias);
            }
        }
    }
    #undef G1_ISSUE
}

// ---------------------------------------------------------------------------
// GEMM2: out = H @ W2 + b2.  H f16 [12288][512], W2T f16 [768][512],
// out f32 [12288][768]. Tile 128x128, BK=64, wave = 64x64 (4x4 frags).
// Proven R5 version (GLL16, linear LDS, 2-phase). Grid 576.
// ---------------------------------------------------------------------------
__global__ __launch_bounds__(256) void gemm2_kernel(
    const _Float16* __restrict__ Hin,
    const _Float16* __restrict__ W2T,
    const float*    __restrict__ b2,
    float*          __restrict__ out)
{
    const int tid  = threadIdx.x;
    const int wid  = tid >> 6;
    const int lane = tid & 63;

    // 576 blocks, 72 per XCD
    const int logical = ((blockIdx.x & 7) * 72) + (blockIdx.x >> 3);
    const int bm = logical / 6;      // 0..95
    const int bn = logical % 6;      // 0..5

    __shared__ _Float16 As[2][128 * 64];   // 16KB per buf
    __shared__ _Float16 Bs[2][128 * 64];

    const int lrow = lane >> 3;
    const int lcol = (lane & 7) * 8;
    const _Float16* ag[4];
    const _Float16* bg[4];
    #pragma unroll
    for (int q = 0; q < 4; ++q) {
        ag[q] = Hin + (size_t)(bm * 128 + (wid + q * 4) * 8 + lrow) * H1 + lcol;
        bg[q] = W2T + (size_t)(bn * 128 + (wid + q * 4) * 8 + lrow) * H1 + lcol;
    }

    #define G2_ISSUE(buf, k0) {                                        \
        _Pragma("unroll")                                              \
        for (int q = 0; q < 4; ++q) {                                  \
            GLL16(ag[q] + (k0), &As[buf][(wid + q * 4) * 512]);        \
            GLL16(bg[q] + (k0), &Bs[buf][(wid + q * 4) * 512]);        \
        }                                                              \
    }

    const int wrow = (wid >> 1) * 64;
    const int wcol = (wid & 1) * 64;
    const int fr   = lane & 15;
    const int fg   = lane >> 4;

    f32x4 acc[4][4] = {};

    G2_ISSUE(0, 0);

    const int NT = H1 / 64;   // 8
    for (int t = 0; t < NT; ++t) {
        __syncthreads();
        if (t + 1 < NT) G2_ISSUE((t + 1) & 1, (t + 1) * 64);
        const int cb = t & 1;
        #pragma unroll
        for (int kk = 0; kk < 2; ++kk) {
            half8 af[4], bf[4];
            #pragma unroll
            for (int i = 0; i < 4; ++i)
                af[i] = *(const half8*)&As[cb][(wrow + i*16 + fr) * 64 + kk*32 + fg*8];
            #pragma unroll
            for (int j = 0; j < 4; ++j)
                bf[j] = *(const half8*)&Bs[cb][(wcol + j*16 + fr) * 64 + kk*32 + fg*8];
            #pragma unroll
            for (int i = 0; i < 4; ++i)
                #pragma unroll
                for (int j = 0; j < 4; ++j)
                    acc[i][j] = __builtin_amdgcn_mfma_f32_16x16x32_f16(af[i], bf[j], acc[i][j], 0, 0, 0);
        }
    }

    #pragma unroll
    for (int i = 0; i < 4; ++i) {
        #pragma unroll
        for (int j = 0; j < 4; ++j) {
            int col = bn * 128 + wcol + j * 16 + fr;
            float bias = b2[col];
            #pragma unroll
            for (int r = 0; r < 4; ++r) {
                int row = bm * 128 + wrow + i * 16 + fg * 4 + r;
                out[(size_t)row * H2 + col] = acc[i][j][r] + bias;
            }
        }
    }
    #undef G2_ISSUE
}

// ---------------------------------------------------------------------------
// Aux outputs: labels / type_ids / att_mask concatenations, written as floats
// ---------------------------------------------------------------------------
__global__ __launch_bounds__(256) void aux_kernel(
    const int* __restrict__ topic_ids,
    const int* __restrict__ input_ids,
    const int* __restrict__ tpw_type_ids,
    const int* __restrict__ type_ids,
    const int* __restrict__ tpw_att_mask,
    const int* __restrict__ attention_mask,
    float* __restrict__ out)
{
    int idx = blockIdx.x * 256 + threadIdx.x;
    if (idx >= MM) return;
    int b = idx / TT, t = idx % TT;
    int lab, ty, mk;
    if (t < PP) {
        lab = topic_ids[b * PP + t];
        ty  = tpw_type_ids[b * PP + t];
        mk  = tpw_att_mask[b * PP + t];
    } else {
        int u = t - PP;
        lab = input_ids[b * LL + u];
        ty  = type_ids[b * LL + u];
        mk  = attention_mask[b * LL + u];
    }
    out[OUT0 + idx]          = (float)lab;
    out[OUT0 + MM + idx]     = (float)ty;
    out[OUT0 + 2 * MM + idx] = (float)mk;
}

extern "C" void kernel_launch(void* const* d_in, const int* in_sizes, int n_in,
                              void* d_out, int out_size, void* d_ws, size_t ws_size,
                              hipStream_t stream) {
    const float* concat_output  = (const float*)d_in[0];
    const int*   input_ids      = (const int*)d_in[1];
    const int*   topic_ids      = (const int*)d_in[2];
    const int*   tpw_att_mask   = (const int*)d_in[3];
    const int*   tpw_type_ids   = (const int*)d_in[4];
    const int*   attention_mask = (const int*)d_in[5];
    const int*   type_ids       = (const int*)d_in[6];
    const float* token_table    = (const float*)d_in[7];
    const float* W1             = (const float*)d_in[8];
    const float* b1             = (const float*)d_in[9];
    const float* W2             = (const float*)d_in[10];
    const float* b2             = (const float*)d_in[11];
    float* out = (float*)d_out;

    _Float16* w1t = (_Float16*)d_ws;            // [512][2048]   2.0 MB
    _Float16* w2t = w1t + (size_t)H1 * DD;      // [768][512]    0.75 MB
    _Float16* Hws = w2t + (size_t)H2 * H1;      // [12288][512]  12.6 MB
    _Float16* A16 = Hws + (size_t)MM * H1;      // [12288][2048] 50.3 MB

    transpose_f16_kernel<<<dim3(H1 / 32, DD / 32), 256, 0, stream>>>(W1, w1t, DD, H1);
    transpose_f16_kernel<<<dim3(H2 / 32, H1 / 32), 256, 0, stream>>>(W2, w2t, H1, H2);
    aux_kernel<<<(MM + 255) / 256, 256, 0, stream>>>(
        topic_ids, input_ids, tpw_type_ids, type_ids, tpw_att_mask, attention_mask, out);
    gather_kernel<<<MM, 256, 0, stream>>>(
        token_table, topic_ids, input_ids, concat_output, A16);

    gemm1_kernel<<<(MM / 64) * (H1 / 256), 256, 0, stream>>>(A16, w1t, b1, Hws);
    gemm2_kernel<<<(MM / 128) * (H2 / 128), 256, 0, stream>>>(Hws, w2t, b2, out);
}

// Round 10
// 110.548 us; speedup vs baseline: 1.2447x; 1.0981x over previous
//
#include <hip/hip_runtime.h>
#include <math.h>

typedef _Float16 half8 __attribute__((ext_vector_type(8)));
typedef float f32x4 __attribute__((ext_vector_type(4)));

// Problem constants
#define BB 32
#define SS 8
#define PP 32
#define SENT 44
#define LL 352          // SS*SENT
#define TT 384          // PP+LL
#define DD 2048
#define H1 512
#define H2 768
#define MM (BB*TT)      // 12288
#define OUT0 (MM*H2)    // 9437184

// async global->LDS, 16B per lane, dest = wave-uniform base + lane*16,
// global source address IS per-lane.
#define GLL16(g, l) __builtin_amdgcn_global_load_lds( \
    (const __attribute__((address_space(1))) void*)(g), \
    (__attribute__((address_space(3))) void*)(l), 16, 0, 0)

// ---------------------------------------------------------------------------
// Transpose + fp32->fp16 convert:  dst[C][R] = (f16) src[R][C]
// ---------------------------------------------------------------------------
__global__ __launch_bounds__(256) void transpose_f16_kernel(
    const float* __restrict__ src, _Float16* __restrict__ dst, int R, int C)
{
    __shared__ float tile[32][33];
    int c0 = blockIdx.x * 32;
    int r0 = blockIdx.y * 32;
    int tx = threadIdx.x & 31;
    int ty = threadIdx.x >> 5;   // 0..7
    #pragma unroll
    for (int i = 0; i < 4; ++i)
        tile[ty + i*8][tx] = src[(size_t)(r0 + ty + i*8) * C + c0 + tx];
    __syncthreads();
    #pragma unroll
    for (int i = 0; i < 4; ++i)
        dst[(size_t)(c0 + ty + i*8) * R + r0 + tx] = (_Float16)tile[tx][ty + i*8];
}

// ---------------------------------------------------------------------------
// Staging macros (reg-staged A rows: fp32 global -> f16 swizzled LDS).
// 4 threads per row, 16 elems each. XOR swizzle (row&7)<<3 in half units.
// ---------------------------------------------------------------------------
#define LOADA_T(S, ap, k0) {                                               \
    const float* _p = (ap) + (k0) + akq;                                   \
    float4 v0 = *(const float4*)(_p);                                      \
    float4 v1 = *(const float4*)(_p + 4);                                  \
    float4 v2 = *(const float4*)(_p + 8);                                  \
    float4 v3 = *(const float4*)(_p + 12);                                 \
    S[0]=v0.x; S[1]=v0.y; S[2]=v0.z; S[3]=v0.w;                            \
    S[4]=v1.x; S[5]=v1.y; S[6]=v1.z; S[7]=v1.w;                            \
    S[8]=v2.x; S[9]=v2.y; S[10]=v2.z; S[11]=v2.w;                          \
    S[12]=v3.x; S[13]=v3.y; S[14]=v3.z; S[15]=v3.w;                        \
}

#define WRITEA_T(S, dst) {                                                 \
    half8 h0, h1;                                                          \
    _Pragma("unroll")                                                      \
    for (int _j = 0; _j < 8; ++_j) { h0[_j] = (_Float16)S[_j];             \
                                     h1[_j] = (_Float16)S[8 + _j]; }       \
    *(half8*)&dst[(arow * 64 + akq) ^ aswz]     = h0;                      \
    *(half8*)&dst[(arow * 64 + akq + 8) ^ aswz] = h1;                      \
}

// ---------------------------------------------------------------------------
// C1 = concat_output @ W1 : [256, 512] fp32.  Tiny MFMA GEMM, grid 16.
// (R6-proven.)
// ---------------------------------------------------------------------------
__global__ __launch_bounds__(256) void c1_kernel(
    const float*    __restrict__ concat_output,
    const _Float16* __restrict__ W1T,
    float*          __restrict__ C1)
{
    const int tid  = threadIdx.x;
    const int wid  = tid >> 6;
    const int lane = tid & 63;
    const int bm = blockIdx.x >> 2;    // 0..3
    const int bn = blockIdx.x & 3;     // 0..3

    __shared__ _Float16 As[2][64 * 64];
    __shared__ _Float16 Bs[2][128 * 64];

    const int arow = tid >> 2;
    const int akq  = (tid & 3) * 16;
    const int aswz = (arow & 7) << 3;
    const float* aptr = concat_output + (size_t)(bm * 64 + arow) * DD;

    const int rl = lane >> 3;
    const int cg = lane & 7;
    const _Float16* bsrc = W1T + (size_t)(bn * 128 + wid * 32 + rl) * DD
                               + ((cg ^ rl) << 3);

    #define C1B(buf, k0) {                                                \
        _Pragma("unroll")                                                 \
        for (int q = 0; q < 4; ++q)                                       \
            GLL16(bsrc + (size_t)q * 8 * DD + (k0),                       \
                  &Bs[buf][(wid * 4 + q) * 512]);                         \
    }

    const int wrow = (wid >> 1) * 32;
    const int wcol = (wid & 1) * 64;
    const int fr   = lane & 15;
    const int fg   = lane >> 4;

    f32x4 acc[2][4] = {};
    float a0[16], a1[16];

    C1B(0, 0);
    LOADA_T(a0, aptr, 0);
    LOADA_T(a1, aptr, 64);
    WRITEA_T(a0, As[0]);
    __syncthreads();

    #define C1_MFMA(buf) {                                                \
        _Pragma("unroll")                                                 \
        for (int kk = 0; kk < 2; ++kk) {                                  \
            half8 af[2], bf[4];                                           \
            _Pragma("unroll")                                             \
            for (int i = 0; i < 2; ++i) {                                 \
                int row = wrow + i * 16 + fr;                             \
                af[i] = *(const half8*)&As[buf][                          \
                    (row * 64 + kk * 32 + fg * 8) ^ ((row & 7) << 3)];    \
            }                                                             \
            _Pragma("unroll")                                             \
            for (int j = 0; j < 4; ++j) {                                 \
                int row = wcol + j * 16 + fr;                             \
                bf[j] = *(const half8*)&Bs[buf][                          \
                    (row * 64 + kk * 32 + fg * 8) ^ ((row & 7) << 3)];    \
            }                                                             \
            _Pragma("unroll")                                             \
            for (int i = 0; i < 2; ++i)                                   \
                _Pragma("unroll")                                         \
                for (int j = 0; j < 4; ++j)                               \
                    acc[i][j] = __builtin_amdgcn_mfma_f32_16x16x32_f16(   \
                        af[i], bf[j], acc[i][j], 0, 0, 0);                \
        }                                                                 \
    }

    for (int tt = 0; tt < 16; ++tt) {
        const int t2 = tt * 2;
        C1B(1, (t2 + 1) * 64);
        if (t2 + 2 < 32) LOADA_T(a0, aptr, (t2 + 2) * 64);
        C1_MFMA(0);
        WRITEA_T(a1, As[1]);
        __syncthreads();
        if (t2 + 2 < 32) C1B(0, (t2 + 2) * 64);
        if (t2 + 3 < 32) LOADA_T(a1, aptr, (t2 + 3) * 64);
        C1_MFMA(1);
        if (t2 + 2 < 32) WRITEA_T(a0, As[0]);
        __syncthreads();
    }

    #pragma unroll
    for (int i = 0; i < 2; ++i)
        #pragma unroll
        for (int j = 0; j < 4; ++j) {
            int col = bn * 128 + wcol + j * 16 + fr;
            #pragma unroll
            for (int r = 0; r < 4; ++r) {
                int row = bm * 64 + wrow + i * 16 + fg * 4 + r;
                C1[(size_t)row * H1 + col] = acc[i][j][r];
            }
        }
    #undef C1B
    #undef C1_MFMA
}

// ---------------------------------------------------------------------------
// GEMM1: H = tanh( gather(table) @ W1 + b1 + C1[crow] )
// R5 structure with BM=48: tile 48x256, BK=64, 256 thr = 4 waves, wave =
// 48x64 (3x4 frags). Grid 512 = EXACTLY 2 blocks/CU (LDS 76KB -> 2 resident).
// A = table rows only (concat removed via C1 fission), reg-staged fp32->f16,
// 2-deep prefetch, swizzled ds_write. B via GLL16, pre-swizzled source.
// ---------------------------------------------------------------------------
__global__ __launch_bounds__(256) void gemm1_kernel(
    const float*    __restrict__ token_table,
    const int*      __restrict__ topic_ids,
    const int*      __restrict__ input_ids,
    const _Float16* __restrict__ W1T,
    const float*    __restrict__ b1,
    const float*    __restrict__ C1,
    _Float16*       __restrict__ Hout)
{
    const int tid  = threadIdx.x;
    const int wid  = tid >> 6;
    const int lane = tid & 63;

    // 512 blocks, 64 per XCD (bijective); both bn of a bm adjacent -> same XCD
    const int logical = ((blockIdx.x & 7) * 64) + (blockIdx.x >> 3);
    const int bm = logical >> 1;     // 0..255
    const int bn = logical & 1;      // 0..1

    __shared__ _Float16 As[2][48 * 64];     //  6KB per buf
    __shared__ _Float16 Bs[2][256 * 64];    // 32KB per buf

    // --- A gather: threads 0..191, 4 threads/row, 16 fp32 each ---
    const int arow = tid >> 2;          // 0..63 (only <48 active)
    const int akq  = (tid & 3) * 16;
    const int aswz = (arow & 7) << 3;
    const bool aact = tid < 192;

    const float* aptr = token_table;
    if (aact) {
        const int m = bm * 48 + arow;
        const int b = m / TT;
        const int t = m % TT;
        const int id = (t < PP) ? topic_ids[b * PP + t]
                                : input_ids[b * LL + (t - PP)];
        aptr = token_table + (size_t)id * DD;
    }

    // --- B staging: per wave 8 GLL16 of 8 rows, pre-swizzled source ---
    const int rl = lane >> 3;           // 0..7
    const int cg = lane & 7;            // 16B granule
    const _Float16* bsrc = W1T + (size_t)(bn * 256 + wid * 64 + rl) * DD
                               + ((cg ^ rl) << 3);

    #define G1B(buf, k0) {                                                \
        _Pragma("unroll")                                                 \
        for (int q = 0; q < 8; ++q)                                       \
            GLL16(bsrc + (size_t)q * 8 * DD + (k0),                       \
                  &Bs[buf][(wid * 64 + q * 8) * 64]);                     \
    }

    #define LOADA(S, k0) { if (aact) LOADA_T(S, aptr, k0) }
    #define WRITEA(S, buf) { if (aact) WRITEA_T(S, As[buf]) }

    // --- compute: wave -> all 48 rows x cols [wid*64, wid*64+64) ---
    const int wcol = wid * 64;
    const int fr   = lane & 15;
    const int fg   = lane >> 4;

    f32x4 acc[3][4] = {};

    #define G1_MFMA(buf) {                                                \
        _Pragma("unroll")                                                 \
        for (int kk = 0; kk < 2; ++kk) {                                  \
            half8 af[3], bf[4];                                           \
            _Pragma("unroll")                                             \
            for (int i = 0; i < 3; ++i) {                                 \
                int row = i * 16 + fr;                                    \
                af[i] = *(const half8*)&As[buf][                          \
                    (row * 64 + kk * 32 + fg * 8) ^ ((row & 7) << 3)];    \
            }                                                             \
            _Pragma("unroll")                                             \
            for (int j = 0; j < 4; ++j) {                                 \
                int row = wcol + j * 16 + fr;                             \
                bf[j] = *(const half8*)&Bs[buf][                          \
                    (row * 64 + kk * 32 + fg * 8) ^ ((row & 7) << 3)];    \
            }                                                             \
            _Pragma("unroll")                                             \
            for (int i = 0; i < 3; ++i)                                   \
                _Pragma("unroll")                                         \
                for (int j = 0; j < 4; ++j)                               \
                    acc[i][j] = __builtin_amdgcn_mfma_f32_16x16x32_f16(   \
                        af[i], bf[j], acc[i][j], 0, 0, 0);                \
        }                                                                 \
    }

    float a0[16], a1[16];

    // prologue
    G1B(0, 0);
    LOADA(a0, 0);
    LOADA(a1, 64);
    WRITEA(a0, 0);
    __syncthreads();

    // 32 K-steps as 16 double-phases (R5-proven schedule)
    for (int tt = 0; tt < 16; ++tt) {
        const int t2 = tt * 2;
        G1B(1, (t2 + 1) * 64);
        if (t2 + 2 < 32) LOADA(a0, (t2 + 2) * 64);
        G1_MFMA(0);
        WRITEA(a1, 1);
        __syncthreads();
        if (t2 + 2 < 32) G1B(0, (t2 + 2) * 64);
        if (t2 + 3 < 32) LOADA(a1, (t2 + 3) * 64);
        G1_MFMA(1);
        if (t2 + 2 < 32) WRITEA(a0, 0);
        __syncthreads();
    }

    // epilogue: + b1 + C1[crow] (input rows only), tanh, f16 store
    #pragma unroll
    for (int i = 0; i < 3; ++i) {
        #pragma unroll
        for (int j = 0; j < 4; ++j) {
            int col = bn * 256 + wcol + j * 16 + fr;
            float bias = b1[col];
            #pragma unroll
            for (int r = 0; r < 4; ++r) {
                int row = bm * 48 + i * 16 + fg * 4 + r;
                int rb = row / TT;
                int rt = row - rb * TT;
                float v = acc[i][j][r] + bias;
                if (rt >= PP)
                    v += C1[(size_t)(rb * SS + (rt - PP) / SENT) * H1 + col];
                Hout[(size_t)row * H1 + col] = (_Float16)tanhf(v);
            }
        }
    }
    #undef G1B
    #undef LOADA
    #undef WRITEA
    #undef G1_MFMA
}

// ---------------------------------------------------------------------------
// GEMM2: out = H @ W2 + b2.  Tile 96x192, BK=64, grid 512 = exactly 2
// blocks/CU (LDS 72KB). Wave = 48x96 (3x6 frags). All-GLL16, both-sides
// swizzle. (R6-proven code.)
// ---------------------------------------------------------------------------
__global__ __launch_bounds__(256) void gemm2_kernel(
    const _Float16* __restrict__ Hin,
    const _Float16* __restrict__ W2T,
    const float*    __restrict__ b2,
    float*          __restrict__ out)
{
    const int tid  = threadIdx.x;
    const int wid  = tid >> 6;
    const int lane = tid & 63;

    // 512 blocks, 64 per XCD
    const int logical = ((blockIdx.x & 7) * 64) + (blockIdx.x >> 3);
    const int bm = logical >> 2;     // 0..127
    const int bn = logical & 3;      // 0..3

    __shared__ _Float16 As[2][96 * 64];    // 12KB per buf
    __shared__ _Float16 Bs[2][192 * 64];   // 24KB per buf

    const int rl = lane >> 3;
    const int cg = lane & 7;
    const _Float16* asrc = Hin + (size_t)(bm * 96 + wid * 24 + rl) * H1
                               + ((cg ^ rl) << 3);
    const _Float16* bsrc = W2T + (size_t)(bn * 192 + wid * 48 + rl) * H1
                               + ((cg ^ rl) << 3);

    #define G2_ISSUE(buf, k0) {                                           \
        _Pragma("unroll")                                                 \
        for (int q = 0; q < 3; ++q)                                       \
            GLL16(asrc + (size_t)q * 8 * H1 + (k0),                       \
                  &As[buf][(wid * 3 + q) * 512]);                         \
        _Pragma("unroll")                                                 \
        for (int q = 0; q < 6; ++q)                                       \
            GLL16(bsrc + (size_t)q * 8 * H1 + (k0),                       \
                  &Bs[buf][(wid * 6 + q) * 512]);                         \
    }

    const int wrow = (wid >> 1) * 48;
    const int wcol = (wid & 1) * 96;
    const int fr   = lane & 15;
    const int fg   = lane >> 4;

    f32x4 acc[3][6] = {};

    G2_ISSUE(0, 0);

    const int NT = H1 / 64;   // 8
    for (int t = 0; t < NT; ++t) {
        __syncthreads();
        if (t + 1 < NT) G2_ISSUE((t + 1) & 1, (t + 1) * 64);
        const int cb = t & 1;
        #pragma unroll
        for (int kk = 0; kk < 2; ++kk) {
            half8 af[3], bf[6];
            #pragma unroll
            for (int i = 0; i < 3; ++i) {
                int row = wrow + i * 16 + fr;
                af[i] = *(const half8*)&As[cb][
                    (row * 64 + kk * 32 + fg * 8) ^ ((row & 7) << 3)];
            }
            #pragma unroll
            for (int j = 0; j < 6; ++j) {
                int row = wcol + j * 16 + fr;
                bf[j] = *(const half8*)&Bs[cb][
                    (row * 64 + kk * 32 + fg * 8) ^ ((row & 7) << 3)];
            }
            #pragma unroll
            for (int i = 0; i < 3; ++i)
                #pragma unroll
                for (int j = 0; j < 6; ++j)
                    acc[i][j] = __builtin_amdgcn_mfma_f32_16x16x32_f16(af[i], bf[j], acc[i][j], 0, 0, 0);
        }
    }

    #pragma unroll
    for (int i = 0; i < 3; ++i) {
        #pragma unroll
        for (int j = 0; j < 6; ++j) {
            int col = bn * 192 + wcol + j * 16 + fr;
            float bias = b2[col];
            #pragma unroll
            for (int r = 0; r < 4; ++r) {
                int row = bm * 96 + wrow + i * 16 + fg * 4 + r;
                out[(size_t)row * H2 + col] = acc[i][j][r] + bias;
            }
        }
    }
    #undef G2_ISSUE
}

// ---------------------------------------------------------------------------
// Aux outputs: labels / type_ids / att_mask concatenations, written as floats
// ---------------------------------------------------------------------------
__global__ __launch_bounds__(256) void aux_kernel(
    const int* __restrict__ topic_ids,
    const int* __restrict__ input_ids,
    const int* __restrict__ tpw_type_ids,
    const int* __restrict__ type_ids,
    const int* __restrict__ tpw_att_mask,
    const int* __restrict__ attention_mask,
    float* __restrict__ out)
{
    int idx = blockIdx.x * 256 + threadIdx.x;
    if (idx >= MM) return;
    int b = idx / TT, t = idx % TT;
    int lab, ty, mk;
    if (t < PP) {
        lab = topic_ids[b * PP + t];
        ty  = tpw_type_ids[b * PP + t];
        mk  = tpw_att_mask[b * PP + t];
    } else {
        int u = t - PP;
        lab = input_ids[b * LL + u];
        ty  = type_ids[b * LL + u];
        mk  = attention_mask[b * LL + u];
    }
    out[OUT0 + idx]          = (float)lab;
    out[OUT0 + MM + idx]     = (float)ty;
    out[OUT0 + 2 * MM + idx] = (float)mk;
}

extern "C" void kernel_launch(void* const* d_in, const int* in_sizes, int n_in,
                              void* d_out, int out_size, void* d_ws, size_t ws_size,
                              hipStream_t stream) {
    const float* concat_output  = (const float*)d_in[0];
    const int*   input_ids      = (const int*)d_in[1];
    const int*   topic_ids      = (const int*)d_in[2];
    const int*   tpw_att_mask   = (const int*)d_in[3];
    const int*   tpw_type_ids   = (const int*)d_in[4];
    const int*   attention_mask = (const int*)d_in[5];
    const int*   type_ids       = (const int*)d_in[6];
    const float* token_table    = (const float*)d_in[7];
    const float* W1             = (const float*)d_in[8];
    const float* b1             = (const float*)d_in[9];
    const float* W2             = (const float*)d_in[10];
    const float* b2             = (const float*)d_in[11];
    float* out = (float*)d_out;

    _Float16* w1t = (_Float16*)d_ws;            // [512][2048]   2.0 MB
    _Float16* w2t = w1t + (size_t)H1 * DD;      // [768][512]    0.75 MB
    _Float16* Hws = w2t + (size_t)H2 * H1;      // [12288][512]  12.6 MB
    float*    C1w = (float*)(Hws + (size_t)MM * H1);  // [256][512] f32 0.5 MB

    transpose_f16_kernel<<<dim3(H1 / 32, DD / 32), 256, 0, stream>>>(W1, w1t, DD, H1);
    transpose_f16_kernel<<<dim3(H2 / 32, H1 / 32), 256, 0, stream>>>(W2, w2t, H1, H2);
    aux_kernel<<<(MM + 255) / 256, 256, 0, stream>>>(
        topic_ids, input_ids, tpw_type_ids, type_ids, tpw_att_mask, attention_mask, out);
    c1_kernel<<<16, 256, 0, stream>>>(concat_output, w1t, C1w);

    gemm1_kernel<<<(MM / 48) * 2, 256, 0, stream>>>(
        token_table, topic_ids, input_ids, w1t, b1, C1w, Hws);
    gemm2_kernel<<<(MM / 96) * (H2 / 192), 256, 0, stream>>>(Hws, w2t, b2, out);
}

// Round 11
// 102.055 us; speedup vs baseline: 1.3483x; 1.0832x over previous
//
#include <hip/hip_runtime.h>
#include <math.h>

typedef _Float16 half8 __attribute__((ext_vector_type(8)));
typedef float f32x4 __attribute__((ext_vector_type(4)));

// Problem constants
#define BB 32
#define SS 8
#define PP 32
#define SENT 44
#define LL 352          // SS*SENT
#define TT 384          // PP+LL
#define DD 2048
#define H1 512
#define H2 768
#define MM (BB*TT)      // 12288
#define OUT0 (MM*H2)    // 9437184

// async global->LDS, 16B per lane, dest = wave-uniform base + lane*16,
// global source address IS per-lane.
#define GLL16(g, l) __builtin_amdgcn_global_load_lds( \
    (const __attribute__((address_space(1))) void*)(g), \
    (__attribute__((address_space(3))) void*)(l), 16, 0, 0)

// ---------------------------------------------------------------------------
// Gather + concat-add + fp32->f16:  A16[m][k], m in [0,12288), k in [0,2048)
// One block per row, 256 threads x 8 elems. Streaming, latency-tolerant
// (many blocks/CU of TLP) — decouples random-row latency from the MFMA loop.
// ---------------------------------------------------------------------------
__global__ __launch_bounds__(256) void gather_kernel(
    const float* __restrict__ token_table,
    const int*   __restrict__ topic_ids,
    const int*   __restrict__ input_ids,
    const float* __restrict__ concat_output,
    _Float16*    __restrict__ A16)
{
    const int m = blockIdx.x;
    const int b = m / TT;
    const int t = m % TT;
    const float* src;
    const float* addp = nullptr;
    if (t < PP) {
        src = token_table + (size_t)topic_ids[b * PP + t] * DD;
    } else {
        int u = t - PP;
        src = token_table + (size_t)input_ids[b * LL + u] * DD;
        addp = concat_output + ((size_t)b * SS + (u / SENT)) * DD;
    }
    _Float16* dst = A16 + (size_t)m * DD;
    const int base = threadIdx.x * 8;
    float4 v0 = *(const float4*)(src + base);
    float4 v1 = *(const float4*)(src + base + 4);
    if (addp) {
        float4 c0 = *(const float4*)(addp + base);
        float4 c1 = *(const float4*)(addp + base + 4);
        v0.x += c0.x; v0.y += c0.y; v0.z += c0.z; v0.w += c0.w;
        v1.x += c1.x; v1.y += c1.y; v1.z += c1.z; v1.w += c1.w;
    }
    half8 h;
    h[0] = (_Float16)v0.x; h[1] = (_Float16)v0.y; h[2] = (_Float16)v0.z; h[3] = (_Float16)v0.w;
    h[4] = (_Float16)v1.x; h[5] = (_Float16)v1.y; h[6] = (_Float16)v1.z; h[7] = (_Float16)v1.w;
    *(half8*)(dst + base) = h;
}

// ---------------------------------------------------------------------------
// Transpose + fp32->fp16 convert:  dst[C][R] = (f16) src[R][C]
// ---------------------------------------------------------------------------
__global__ __launch_bounds__(256) void transpose_f16_kernel(
    const float* __restrict__ src, _Float16* __restrict__ dst, int R, int C)
{
    __shared__ float tile[32][33];
    int c0 = blockIdx.x * 32;
    int r0 = blockIdx.y * 32;
    int tx = threadIdx.x & 31;
    int ty = threadIdx.x >> 5;   // 0..7
    #pragma unroll
    for (int i = 0; i < 4; ++i)
        tile[ty + i*8][tx] = src[(size_t)(r0 + ty + i*8) * C + c0 + tx];
    __syncthreads();
    #pragma unroll
    for (int i = 0; i < 4; ++i)
        dst[(size_t)(c0 + ty + i*8) * R + r0 + tx] = (_Float16)tile[tx][ty + i*8];
}

// ---------------------------------------------------------------------------
// GEMM1: H = tanh( A16 @ W1 + b1 ).  A16 f16 [12288][2048], W1T f16
// [512][2048], H f16 [12288][512].
// MAX-OCCUPANCY variant: tile 64x64, BK=64, 256 thr = 4 waves, wave = 32x32
// (2x2 frags of 16x16x32). LDS = 32KB -> 5 blocks/CU resident (20 waves/CU):
// per-step vmcnt drains of different blocks overlap (m114 TLP mechanism),
// which R7/R8 proved cannot be achieved by in-block pipelining at this size.
// All-GLL16 staging, both-sides XOR swizzle (proven R5/R9 pair).
// Grid 1536 = 192 bm x 8 bn, XCD-chunked: the 8 bn of a bm land on one XCD
// -> A-panel read once into that XCD's L2, W1T (2MB) L2-resident.
// ---------------------------------------------------------------------------
__global__ __launch_bounds__(256) void gemm1_kernel(
    const _Float16* __restrict__ A16,
    const _Float16* __restrict__ W1T,
    const float*    __restrict__ b1,
    _Float16*       __restrict__ Hout)
{
    const int tid  = threadIdx.x;
    const int wid  = tid >> 6;
    const int lane = tid & 63;

    // 1536 blocks, 192 per XCD (bijective); 8 bn of a bm logical-adjacent.
    const int logical = ((blockIdx.x & 7) * 192) + (blockIdx.x >> 3);
    const int bm = logical >> 3;     // 0..191
    const int bn = logical & 7;      // 0..7

    __shared__ _Float16 As[2][64 * 64];     // 8KB per buf
    __shared__ _Float16 Bs[2][64 * 64];     // 8KB per buf

    // staging: 8 rows per GLL16, granule-swizzled global source
    const int rl = lane >> 3;            // 0..7 row within 8-row chunk
    const int cg = lane & 7;             // 16B granule within 128B row
    const _Float16* asrc = A16 + (size_t)(bm * 64 + wid * 16 + rl) * DD
                               + ((cg ^ rl) << 3);
    const _Float16* bsrc = W1T + (size_t)(bn * 64 + wid * 16 + rl) * DD
                               + ((cg ^ rl) << 3);

    #define G1_ISSUE(buf, k0) {                                            \
        _Pragma("unroll")                                                  \
        for (int q = 0; q < 2; ++q) {                                      \
            GLL16(asrc + (size_t)q * 8 * DD + (k0),                        \
                  &As[buf][(wid * 16 + q * 8) * 64]);                      \
            GLL16(bsrc + (size_t)q * 8 * DD + (k0),                        \
                  &Bs[buf][(wid * 16 + q * 8) * 64]);                      \
        }                                                                  \
    }

    // compute: wave -> 32 rows x 32 cols (2x2 frags of 16x16x32)
    const int wrow = (wid >> 1) * 32;
    const int wcol = (wid & 1) * 32;
    const int fr   = lane & 15;
    const int fg   = lane >> 4;

    f32x4 acc[2][2] = {};

    G1_ISSUE(0, 0);

    const int NT = DD / 64;   // 32
    for (int t = 0; t < NT; ++t) {
        __syncthreads();                     // drains vmcnt: buf[t&1] ready
        if (t + 1 < NT) G1_ISSUE((t + 1) & 1, (t + 1) * 64);
        const int cb = t & 1;
        #pragma unroll
        for (int kk = 0; kk < 2; ++kk) {
            half8 af[2], bf[2];
            #pragma unroll
            for (int i = 0; i < 2; ++i) {
                int row = wrow + i * 16 + fr;
                af[i] = *(const half8*)&As[cb][
                    (row * 64 + kk * 32 + fg * 8) ^ ((row & 7) << 3)];
            }
            #pragma unroll
            for (int j = 0; j < 2; ++j) {
                int row = wcol + j * 16 + fr;
                bf[j] = *(const half8*)&Bs[cb][
                    (row * 64 + kk * 32 + fg * 8) ^ ((row & 7) << 3)];
            }
            #pragma unroll
            for (int i = 0; i < 2; ++i)
                #pragma unroll
                for (int j = 0; j < 2; ++j)
                    acc[i][j] = __builtin_amdgcn_mfma_f32_16x16x32_f16(
                        af[i], bf[j], acc[i][j], 0, 0, 0);
        }
    }

    // epilogue: bias + tanh -> f16 H
    #pragma unroll
    for (int i = 0; i < 2; ++i) {
        #pragma unroll
        for (int j = 0; j < 2; ++j) {
            int col = bn * 64 + wcol + j * 16 + fr;
            float bias = b1[col];
            #pragma unroll
            for (int r = 0; r < 4; ++r) {
                int row = bm * 64 + wrow + i * 16 + fg * 4 + r;
                Hout[(size_t)row * H1 + col] = (_Float16)tanhf(acc[i][j][r] + bias);
            }
        }
    }
    #undef G1_ISSUE
}

// ---------------------------------------------------------------------------
// GEMM2: out = H @ W2 + b2.  Tile 96x192, BK=64, grid 512 = exactly 2
// blocks/CU (LDS 72KB). Wave = 48x96 (3x6 frags). All-GLL16, both-sides
// swizzle. (R6/R10-proven code.)
// ---------------------------------------------------------------------------
__global__ __launch_bounds__(256) void gemm2_kernel(
    const _Float16* __restrict__ Hin,
    const _Float16* __restrict__ W2T,
    const float*    __restrict__ b2,
    float*          __restrict__ out)
{
    const int tid  = threadIdx.x;
    const int wid  = tid >> 6;
    const int lane = tid & 63;

    // 512 blocks, 64 per XCD
    const int logical = ((blockIdx.x & 7) * 64) + (blockIdx.x >> 3);
    const int bm = logical >> 2;     // 0..127
    const int bn = logical & 3;      // 0..3

    __shared__ _Float16 As[2][96 * 64];    // 12KB per buf
    __shared__ _Float16 Bs[2][192 * 64];   // 24KB per buf

    const int rl = lane >> 3;
    const int cg = lane & 7;
    const _Float16* asrc = Hin + (size_t)(bm * 96 + wid * 24 + rl) * H1
                               + ((cg ^ rl) << 3);
    const _Float16* bsrc = W2T + (size_t)(bn * 192 + wid * 48 + rl) * H1
                               + ((cg ^ rl) << 3);

    #define G2_ISSUE(buf, k0) {                                           \
        _Pragma("unroll")                                                 \
        for (int q = 0; q < 3; ++q)                                       \
            GLL16(asrc + (size_t)q * 8 * H1 + (k0),                       \
                  &As[buf][(wid * 3 + q) * 512]);                         \
        _Pragma("unroll")                                                 \
        for (int q = 0; q < 6; ++q)                                       \
            GLL16(bsrc + (size_t)q * 8 * H1 + (k0),                       \
                  &Bs[buf][(wid * 6 + q) * 512]);                         \
    }

    const int wrow = (wid >> 1) * 48;
    const int wcol = (wid & 1) * 96;
    const int fr   = lane & 15;
    const int fg   = lane >> 4;

    f32x4 acc[3][6] = {};

    G2_ISSUE(0, 0);

    const int NT = H1 / 64;   // 8
    for (int t = 0; t < NT; ++t) {
        __syncthreads();
        if (t + 1 < NT) G2_ISSUE((t + 1) & 1, (t + 1) * 64);
        const int cb = t & 1;
        #pragma unroll
        for (int kk = 0; kk < 2; ++kk) {
            half8 af[3], bf[6];
            #pragma unroll
            for (int i = 0; i < 3; ++i) {
                int row = wrow + i * 16 + fr;
                af[i] = *(const half8*)&As[cb][
                    (row * 64 + kk * 32 + fg * 8) ^ ((row & 7) << 3)];
            }
            #pragma unroll
            for (int j = 0; j < 6; ++j) {
                int row = wcol + j * 16 + fr;
                bf[j] = *(const half8*)&Bs[cb][
                    (row * 64 + kk * 32 + fg * 8) ^ ((row & 7) << 3)];
            }
            #pragma unroll
            for (int i = 0; i < 3; ++i)
                #pragma unroll
                for (int j = 0; j < 6; ++j)
                    acc[i][j] = __builtin_amdgcn_mfma_f32_16x16x32_f16(af[i], bf[j], acc[i][j], 0, 0, 0);
        }
    }

    #pragma unroll
    for (int i = 0; i < 3; ++i) {
        #pragma unroll
        for (int j = 0; j < 6; ++j) {
            int col = bn * 192 + wcol + j * 16 + fr;
            float bias = b2[col];
            #pragma unroll
            for (int r = 0; r < 4; ++r) {
                int row = bm * 96 + wrow + i * 16 + fg * 4 + r;
                out[(size_t)row * H2 + col] = acc[i][j][r] + bias;
            }
        }
    }
    #undef G2_ISSUE
}

// ---------------------------------------------------------------------------
// Aux outputs: labels / type_ids / att_mask concatenations, written as floats
// ---------------------------------------------------------------------------
__global__ __launch_bounds__(256) void aux_kernel(
    const int* __restrict__ topic_ids,
    const int* __restrict__ input_ids,
    const int* __restrict__ tpw_type_ids,
    const int* __restrict__ type_ids,
    const int* __restrict__ tpw_att_mask,
    const int* __restrict__ attention_mask,
    float* __restrict__ out)
{
    int idx = blockIdx.x * 256 + threadIdx.x;
    if (idx >= MM) return;
    int b = idx / TT, t = idx % TT;
    int lab, ty, mk;
    if (t < PP) {
        lab = topic_ids[b * PP + t];
        ty  = tpw_type_ids[b * PP + t];
        mk  = tpw_att_mask[b * PP + t];
    } else {
        int u = t - PP;
        lab = input_ids[b * LL + u];
        ty  = type_ids[b * LL + u];
        mk  = attention_mask[b * LL + u];
    }
    out[OUT0 + idx]          = (float)lab;
    out[OUT0 + MM + idx]     = (float)ty;
    out[OUT0 + 2 * MM + idx] = (float)mk;
}

extern "C" void kernel_launch(void* const* d_in, const int* in_sizes, int n_in,
                              void* d_out, int out_size, void* d_ws, size_t ws_size,
                              hipStream_t stream) {
    const float* concat_output  = (const float*)d_in[0];
    const int*   input_ids      = (const int*)d_in[1];
    const int*   topic_ids      = (const int*)d_in[2];
    const int*   tpw_att_mask   = (const int*)d_in[3];
    const int*   tpw_type_ids   = (const int*)d_in[4];
    const int*   attention_mask = (const int*)d_in[5];
    const int*   type_ids       = (const int*)d_in[6];
    const float* token_table    = (const float*)d_in[7];
    const float* W1             = (const float*)d_in[8];
    const float* b1             = (const float*)d_in[9];
    const float* W2             = (const float*)d_in[10];
    const float* b2             = (const float*)d_in[11];
    float* out = (float*)d_out;

    _Float16* w1t = (_Float16*)d_ws;            // [512][2048]   2.0 MB
    _Float16* w2t = w1t + (size_t)H1 * DD;      // [768][512]    0.75 MB
    _Float16* Hws = w2t + (size_t)H2 * H1;      // [12288][512]  12.6 MB
    _Float16* A16 = Hws + (size_t)MM * H1;      // [12288][2048] 50.3 MB

    transpose_f16_kernel<<<dim3(H1 / 32, DD / 32), 256, 0, stream>>>(W1, w1t, DD, H1);
    transpose_f16_kernel<<<dim3(H2 / 32, H1 / 32), 256, 0, stream>>>(W2, w2t, H1, H2);
    aux_kernel<<<(MM + 255) / 256, 256, 0, stream>>>(
        topic_ids, input_ids, tpw_type_ids, type_ids, tpw_att_mask, attention_mask, out);
    gather_kernel<<<MM, 256, 0, stream>>>(
        token_table, topic_ids, input_ids, concat_output, A16);

    gemm1_kernel<<<(MM / 64) * (H1 / 64), 256, 0, stream>>>(A16, w1t, b1, Hws);
    gemm2_kernel<<<(MM / 96) * (H2 / 192), 256, 0, stream>>>(Hws, w2t, b2, out);
}